// Round 17
// baseline (441.110 us; speedup 1.0000x reference)
//
#include <hip/hip_runtime.h>
#include <cstdint>
#include <cstddef>

#define KBOX 4096
#define NMS_THRESH 0.6f

typedef unsigned long long u64;

// ---- workspace layout (bytes) ----
static constexpr size_t WS_SB   = 0;        // float4[KBOX]   64 KB  sorted boxes
static constexpr size_t WS_AREA = 65536;    // float[KBOX]    16 KB  sorted areas
static constexpr size_t WS_SS   = 81920;    // float[KBOX]    16 KB  sorted scores
static constexpr size_t WS_ORD  = 98304;    // int[KBOX]      16 KB  sorted orig idx
static constexpr size_t WS_KEYS = 114688;   // u64[KBOX]      32 KB  sort keys
static constexpr size_t WS_MASK = 147456;   // u64[KBOX*64]    2 MB  iou mask

// async global->LDS DMA: 64 lanes x 16 B = 1 KB per call.
// LDS dest must be wave-uniform (HW adds lane*16); global src is per-lane.
__device__ __forceinline__ void gload_lds16(const void* g, void* l) {
    __builtin_amdgcn_global_load_lds(
        (const __attribute__((address_space(1))) void*)g,
        (__attribute__((address_space(3))) void*)l, 16, 0, 0);
}

// Kernel 1: build sort keys. key = (score_bits<<32) | (0xFFFFFFFF - p).
// Scores are positive floats -> uint bit-pattern is order-preserving; low word
// makes keys UNIQUE and reproduces stable argsort(-scores) tie-breaking.
__global__ __launch_bounds__(256) void k_keys(const float* __restrict__ yolo,
                                              const int* __restrict__ bidx,
                                              u64* __restrict__ keys) {
    int p = blockIdx.x * 256 + threadIdx.x;
    size_t idx = (size_t)(unsigned)bidx[p];
    float s = yolo[idx * 5 + 4];
    keys[p] = ((u64)__float_as_uint(s) << 32)
            | (u64)(0xFFFFFFFFu - (unsigned)p);
}

// Kernel 2: rank-sort. Keys are unique, so rank[p] = #{q : key[q] > key[p]}
// is the exact stable descending permutation. One wave per p; lanes scan 64
// keys per step via ballot+popc (keys are L2/L1-resident, 32 KB).
// Lane 0 then gathers the box and writes sorted arrays at position rank.
__global__ __launch_bounds__(256) void k_rank(const u64* __restrict__ keys,
                                              const float* __restrict__ yolo,
                                              const int* __restrict__ bidx,
                                              float4* __restrict__ sb,
                                              float* __restrict__ area,
                                              float* __restrict__ ss,
                                              int* __restrict__ sord) {
    #pragma clang fp contract(off)
    int gid = blockIdx.x * 256 + threadIdx.x;
    int p = gid >> 6;          // wave-uniform
    int lane = gid & 63;

    u64 kp = keys[p];
    int cnt = 0;
    for (int k = 0; k < 64; ++k) {
        u64 kq = keys[k * 64 + lane];            // coalesced
        cnt += __popcll(__ballot(kq > kp));      // wave-uniform increment
    }

    if (lane == 0) {
        int r = cnt;                              // rank = sorted position
        size_t idx = (size_t)(unsigned)bidx[p];
        float x1 = yolo[idx * 5 + 0];
        float y1 = yolo[idx * 5 + 1];
        float x2 = yolo[idx * 5 + 2];
        float y2 = yolo[idx * 5 + 3];
        float s  = __uint_as_float((unsigned)(kp >> 32));
        sb[r] = make_float4(x1, y1, x2, y2);
        area[r] = (x2 - x1 + 1.0f) * (y2 - y1 + 1.0f);   // same op order as reference
        ss[r] = s;
        sord[r] = p;
    }
}

// Kernel 3: one wave per row i. Step k: lanes compute IoU(i, k*64+lane);
// __ballot gives mask word k of row i. Lane k keeps word k, coalesced store.
__global__ __launch_bounds__(256) void k_mask(const float4* __restrict__ sb,
                                              const float* __restrict__ area,
                                              u64* __restrict__ mask) {
    #pragma clang fp contract(off)
    int gid = blockIdx.x * 256 + threadIdx.x;
    int i = gid >> 6;          // wave-uniform
    int lane = gid & 63;

    float4 bi = sb[i];
    float ai = area[i];
    u64 myword = 0ull;

    for (int k = 0; k < 64; ++k) {
        int j = k * 64 + lane;
        float4 bj = sb[j];
        float xx1 = fmaxf(bi.x, bj.x);
        float yy1 = fmaxf(bi.y, bj.y);
        float xx2 = fminf(bi.z, bj.z);
        float yy2 = fminf(bi.w, bj.w);
        float w = fmaxf(0.0f, xx2 - xx1 + 1.0f);
        float h = fmaxf(0.0f, yy2 - yy1 + 1.0f);
        float inter = w * h;
        float uni = (ai + area[j]) - inter;   // areas_i + areas_j - inter
        float iou = inter / uni;
        bool pred = (iou >= NMS_THRESH) && (j > i);
        u64 bal = __ballot(pred);
        if (k == lane) myword = bal;
    }
    mask[(size_t)i * 64 + lane] = myword;
}

// Kernel 4 (fused reduce + output), one block of 256 threads (4 waves).
// Per chunk c (64 rows):
//   * all waves issue async DMA prefetch of chunk c+1 (latency hides under compute)
//   * all waves redundantly run the greedy chain in pick-lowest-undecided form:
//       undec = ~sup_init; loop: u0=ctz(undec); kept|=bit; undec &= ~shfl(bcu,u0)
//     -> ONE 64-bit shfl per KEPT row (~30/chunk) instead of 64 dependent
//        shfl steps (the 214us bottleneck: ~8k cyc/chunk of serialized LDS ops).
//   * Phase B split 4 ways: wave w ORs kept rows [16w,16w+16) into its
//     lane-sliced partial remv (16 independent ds_read_b64 + masked OR).
//   * handoff: lane c+1 of each wave writes its partial word to hand[(c+1)&1][w];
//     next chunk's sup_init = OR of the 4 words (double-buffered vs in-chunk race).
__global__ __launch_bounds__(256) void k_reduce_out(const u64* __restrict__ mask,
                                                    const float4* __restrict__ sb,
                                                    const float* __restrict__ ss,
                                                    const int* __restrict__ sord,
                                                    float* __restrict__ out) {
    __shared__ u64 stage[2][64 * 64];   // 2 x 32 KB
    __shared__ u64 hand[2][4];          // per-wave partial remv word handoff
    __shared__ u64 keep_lds[64];
    const int tid = threadIdx.x;
    const int wid = tid >> 6;           // 0..3, wave-uniform
    const int lane = tid & 63;

    // preload chunk 0: 32 x 1KB DMA blocks over all 4 waves
    {
        const char* src = (const char*)mask;
        char* dst = (char*)stage[0];
        for (int b = wid; b < 32; b += 4)
            gload_lds16(src + b * 1024 + lane * 16, dst + b * 1024);
    }
    if (tid < 8) hand[tid >> 2][tid & 3] = 0ull;
    __syncthreads();

    u64 partial = 0ull;   // this wave's share of remv (lane-sliced words)

    for (int c = 0; c < 64; ++c) {
        // issue async prefetch of chunk c+1 (fire-and-forget; drained at barrier)
        if (c + 1 < 64) {
            const char* src = (const char*)(mask + (size_t)(c + 1) * 4096);
            char* dst = (char*)stage[(c + 1) & 1];
            for (int b = wid; b < 32; b += 4)
                gload_lds16(src + b * 1024 + lane * 16, dst + b * 1024);
        }

        const u64* buf = stage[c & 1];

        // sup_init: full remv word c = OR of the 4 per-wave partial words
        u64 sup0 = hand[c & 1][0] | hand[c & 1][1] | hand[c & 1][2] | hand[c & 1][3];

        // lane u holds row u's in-chunk word (who row u suppresses within chunk)
        u64 bcu = buf[(lane << 6) + c];

        // greedy chain, pick-lowest-undecided (uniform; ~1 shfl per kept row)
        u64 undec = ~sup0;
        u64 kept = 0ull;
        while (undec) {
            int u0 = __builtin_ctzll(undec);
            u64 supset = __shfl(bcu, u0);          // row u0's suppression set
            kept |= 1ull << u0;
            undec &= ~(supset | (1ull << u0));
        }

        // Phase B: this wave ORs its 16 rows (branchless scalar-masked)
        u64 acc = 0ull;
        #pragma unroll
        for (int k = 0; k < 16; ++k) {
            int u = (wid << 4) + k;
            u64 m = buf[(u << 6) | lane];          // independent ds_read_b64
            acc |= m & (0ull - ((kept >> u) & 1ull));
        }
        partial |= acc;

        if (wid == 0 && lane == 0) keep_lds[c] = kept;
        if (lane == c + 1) hand[(c + 1) & 1][wid] = partial;  // next sup_init

        __syncthreads();   // drains DMA; publishes hand/keep; flips buffers
    }

    // bbox_num: sum of popcounts of keep words (wave 0)
    if (tid < 64) {
        int cnt = __popcll(keep_lds[tid]);
        for (int off = 32; off > 0; off >>= 1) cnt += __shfl_down(cnt, off);
        if (tid == 0) out[(size_t)KBOX * 6] = (float)cnt;
    }
    __syncthreads();

    // output fan-out: bbox_pred rows + nms_keep_idx (all elements every call)
    for (int p = tid; p < KBOX; p += 256) {
        bool keep = (keep_lds[p >> 6] >> (p & 63)) & 1ull;
        float4 b = sb[p];
        float s = ss[p];
        int o = sord[p];

        float* row = out + (size_t)p * 6;
        row[0] = 0.0f;
        row[1] = keep ? s   : 0.0f;
        row[2] = keep ? b.x : 0.0f;
        row[3] = keep ? b.y : 0.0f;
        row[4] = keep ? b.z : 0.0f;
        row[5] = keep ? b.w : 0.0f;

        out[(size_t)KBOX * 6 + 1 + p] = keep ? (float)o : -1.0f;
    }
}

extern "C" void kernel_launch(void* const* d_in, const int* in_sizes, int n_in,
                              void* d_out, int out_size, void* d_ws, size_t ws_size,
                              hipStream_t stream) {
    const float* yolo = (const float*)d_in[0];   // [4e6, 5] f32
    const int* bidx   = (const int*)d_in[1];     // [4096] i32
    float* out = (float*)d_out;                  // 4096*6 + 1 + 4096 floats

    char* ws = (char*)d_ws;                      // ~2.15 MB used
    float4* sb  = (float4*)(ws + WS_SB);
    float* area = (float*)(ws + WS_AREA);
    float* ss   = (float*)(ws + WS_SS);
    int* sord   = (int*)(ws + WS_ORD);
    u64* keys   = (u64*)(ws + WS_KEYS);
    u64* mask   = (u64*)(ws + WS_MASK);

    k_keys<<<KBOX / 256, 256, 0, stream>>>(yolo, bidx, keys);
    k_rank<<<(KBOX * 64) / 256, 256, 0, stream>>>(keys, yolo, bidx, sb, area, ss, sord);
    k_mask<<<(KBOX * 64) / 256, 256, 0, stream>>>(sb, area, mask);
    k_reduce_out<<<1, 256, 0, stream>>>(mask, sb, ss, sord, out);
}